// Round 2
// baseline (1274.497 us; speedup 1.0000x reference)
//
#include <hip/hip_runtime.h>
#include <hip/hip_bf16.h>
#include <hip/hip_fp16.h>

#define N_NODES 100000
#define N_EDGES 3200000
#define F_IN    128
#define F_H     64

#define NBUCK 256
#define NPB   391            // ceil(N_NODES / NBUCK); last bucket short
#define SRC_BITS 17          // N_NODES < 2^17; pack = (dstLocal<<17)|src
#define CH_SHIFT 11          // src-chunk = src>>11 (2048 nodes = 256 KB of hs)
#define NCH 49               // ceil(100000/2048)

// ---------------------------------------------------------------------------
// Bucket-level histogram: 256 bins, LDS-aggregated (50K global atomics total)
// ---------------------------------------------------------------------------
#define BH_T 256
#define BH_C 16384           // edges per block -> 196 blocks
__global__ __launch_bounds__(BH_T) void k_bhist(const int* __restrict__ dst,
                                                int* __restrict__ bcount) {
    __shared__ int lc[NBUCK];
    int t = threadIdx.x;
    lc[t] = 0;
    __syncthreads();
    long long e0 = (long long)blockIdx.x * BH_C;
    long long e1 = e0 + BH_C; if (e1 > N_EDGES) e1 = N_EDGES;
    for (long long e = e0 + t; e < e1; e += BH_T)
        atomicAdd(&lc[dst[e] / NPB], 1);
    __syncthreads();
    int c = lc[t];
    if (c) atomicAdd(&bcount[t], c);
}

// ---------------------------------------------------------------------------
// Scan of 256 bucket counts -> bucket bases + partA cursors
// ---------------------------------------------------------------------------
__global__ __launch_bounds__(NBUCK) void k_bscan(const int* __restrict__ bcount,
                                                 int* __restrict__ bbase,
                                                 int* __restrict__ bcur) {
    __shared__ int s[NBUCK];
    int t = threadIdx.x;
    int c = bcount[t];
    s[t] = c;
    __syncthreads();
    for (int off = 1; off < NBUCK; off <<= 1) {
        int v = (t >= off) ? s[t - off] : 0;
        __syncthreads();
        s[t] += v;
        __syncthreads();
    }
    int ex = s[t] - c;
    bbase[t] = ex;
    bcur[t]  = ex;
    if (t == NBUCK - 1) bbase[NBUCK] = s[t];   // = N_EDGES
}

// ---------------------------------------------------------------------------
// wc2 = W2^T Wc (64-vector), c0 = Wc.b2 + bc  — collapses layer2+head
// ---------------------------------------------------------------------------
__global__ __launch_bounds__(64) void k_wc2(const float* __restrict__ W2,
                                            const float* __restrict__ Wc,
                                            const float* __restrict__ b2,
                                            const float* __restrict__ bc,
                                            float* __restrict__ wc2,
                                            float* __restrict__ c0) {
    int k = threadIdx.x;
    float s = 0.0f;
#pragma unroll 8
    for (int f = 0; f < F_H; f++) s += Wc[f] * W2[f * F_H + k];
    wc2[k] = s;
    float p = Wc[k] * b2[k];
#pragma unroll
    for (int off = 32; off > 0; off >>= 1) p += __shfl_xor(p, off, 64);
    if (k == 0) c0[0] = p + bc[0];
}

// ---------------------------------------------------------------------------
// Pass A: partition edges into NBUCK dst-range buckets; emit packed
// (dstLocal<<17)|src words (LDS-staged, coalesced out)
// ---------------------------------------------------------------------------
#define PA_T   256
#define PA_C   4096
#define PA_PER (PA_C / PA_T)   // 16
__global__ __launch_bounds__(PA_T) void k_partA(const int* __restrict__ src,
                                                const int* __restrict__ dst,
                                                int* __restrict__ bucket_cursor,
                                                int* __restrict__ packT) {
    __shared__ int lcount[NBUCK];
    __shared__ int lstart[NBUCK];
    __shared__ int loffs[NBUCK];
    __shared__ int lbase[NBUCK];
    __shared__ int s_pack[PA_C];
    __shared__ unsigned char s_bkt[PA_C];
    __shared__ int ltot;
    int t = threadIdx.x;
    long long e0 = (long long)blockIdx.x * PA_C;
    if (t < NBUCK) lcount[t] = 0;
    __syncthreads();
    int ep[PA_PER];
    short eb[PA_PER];
#pragma unroll
    for (int i = 0; i < PA_PER; i++) {
        long long e = e0 + i * PA_T + t;
        if (e < N_EDGES) {
            int es = src[e], ed = dst[e];
            int b = ed / NPB;
            eb[i] = (short)b;
            ep[i] = ((ed - b * NPB) << SRC_BITS) | es;
            atomicAdd(&lcount[b], 1);
        } else eb[i] = -1;
    }
    __syncthreads();
    // exclusive scan of lcount (256) by wave 0: 4 serial/lane + shfl scan
    if (t < 64) {
        int base = t * 4;
        int c0 = lcount[base], c1 = lcount[base + 1], c2 = lcount[base + 2], c3 = lcount[base + 3];
        int ssum = c0 + c1 + c2 + c3;
        int sc = ssum;
#pragma unroll
        for (int off = 1; off < 64; off <<= 1) {
            int v = __shfl_up(sc, off, 64);
            if (t >= off) sc += v;
        }
        int ex = sc - ssum;
        lstart[base]     = ex;
        lstart[base + 1] = ex + c0;
        lstart[base + 2] = ex + c0 + c1;
        lstart[base + 3] = ex + c0 + c1 + c2;
        if (t == 63) ltot = sc;
    }
    __syncthreads();
    if (t < NBUCK) {
        loffs[t] = lstart[t];
        int c = lcount[t];
        lbase[t] = c ? atomicAdd(&bucket_cursor[t], c) : 0;
    }
    __syncthreads();
#pragma unroll
    for (int i = 0; i < PA_PER; i++) {
        if (eb[i] >= 0) {
            int idx = atomicAdd(&loffs[eb[i]], 1);
            s_pack[idx] = ep[i];
            s_bkt[idx] = (unsigned char)eb[i];
        }
    }
    __syncthreads();
    int tot = ltot;
    for (int i = t; i < tot; i += PA_T) {
        int b = s_bkt[i];
        int addr = lbase[b] + (i - lstart[b]);
        packT[addr] = s_pack[i];
    }
}

// ---------------------------------------------------------------------------
// Pass B: per-bucket counting sort of packed words by SRC-CHUNK (ascending
// src order within the bucket -> sequential hs sweep in k_agg1), plus
// derives dinv[node] from the per-dst histogram.
// ---------------------------------------------------------------------------
#define PB_T   1024
#define PB_CAP 16384
__global__ __launch_bounds__(PB_T) void k_partB(const int* __restrict__ bbase,
                                                const int* __restrict__ packT,
                                                float* __restrict__ dinv,
                                                int* __restrict__ epk) {
    __shared__ int lhist[NPB];
    __shared__ int chist[64];
    __shared__ int ccur[64];
    __shared__ int s_out[PB_CAP];
    int b = blockIdx.x;
    int node0 = b * NPB;
    int node1 = min(node0 + NPB, N_NODES);
    int nloc = node1 - node0;
    int beg = bbase[b];
    int end = bbase[b + 1];
    int len = end - beg;
    int t = threadIdx.x;
    const int SMASK = (1 << SRC_BITS) - 1;

    for (int i = t; i < NPB; i += PB_T) lhist[i] = 0;
    if (t < 64) chist[t] = 0;
    __syncthreads();
    for (int i = t; i < len; i += PB_T) {
        int pk = packT[beg + i];
        atomicAdd(&lhist[pk >> SRC_BITS], 1);
        atomicAdd(&chist[(pk & SMASK) >> CH_SHIFT], 1);
    }
    __syncthreads();
    if (t < 64) {   // exclusive scan of 49 chunk counters via shfl
        int c = chist[t];
        int sc = c;
#pragma unroll
        for (int off = 1; off < 64; off <<= 1) {
            int v = __shfl_up(sc, off, 64);
            if (t >= off) sc += v;
        }
        ccur[t] = sc - c;
    }
    __syncthreads();
    // dinv from in-degree (+1 self-loop)
    for (int i = t; i < nloc; i += PB_T)
        dinv[node0 + i] = rsqrtf((float)(lhist[i] + 1));
    if (len <= PB_CAP) {
        for (int i = t; i < len; i += PB_T) {
            int pk = packT[beg + i];
            int idx = atomicAdd(&ccur[(pk & SMASK) >> CH_SHIFT], 1);
            s_out[idx] = pk;
        }
        __syncthreads();
        for (int i = t; i < len; i += PB_T)
            epk[beg + i] = s_out[i];
    } else {    // statistically never (34 sigma): direct global scatter
        for (int i = t; i < len; i += PB_T) {
            int pk = packT[beg + i];
            int idx = atomicAdd(&ccur[(pk & SMASK) >> CH_SHIFT], 1);
            epk[beg + idx] = pk;
        }
    }
}

// ---------------------------------------------------------------------------
// Layer-1 GEMM: hs16 = fp16( (x @ W1^T) * dinv )
// Register-tiled: block = 256 thr (4 waves), 128 nodes/block.
// ---------------------------------------------------------------------------
#define GT   256
#define NTB  128     // nodes per block
#define KT   64      // k-tile (2 passes for F_IN=128)
#define WTS  68      // wT stride (words)

__global__ __launch_bounds__(GT) void k_gemm1(const float* __restrict__ x,
                                              const float* __restrict__ W1,
                                              const float* __restrict__ dinv,
                                              __half* __restrict__ hs) {
    __shared__ float wT[KT * WTS];     // 17.4 KB
    __shared__ float xT[KT * NTB];     // 32 KB
    int t = threadIdx.x;
    int node0 = blockIdx.x * NTB;
    int lane = t & 63, wv = t >> 6;
    int fi = lane & 15, ni = lane >> 4;
    int n0 = wv * 32 + ni * 8;

    float acc[4][8];
#pragma unroll
    for (int r = 0; r < 4; r++)
#pragma unroll
        for (int c = 0; c < 8; c++) acc[r][c] = 0.0f;

    for (int p = 0; p < 2; p++) {
        int k0 = p * KT;
        if (p) __syncthreads();
        {
            int f = t & 63, kq = t >> 6;
            const float4* wp = (const float4*)&W1[(size_t)f * F_IN + k0 + kq * 16];
#pragma unroll
            for (int j = 0; j < 4; j++) {
                float4 v = wp[j];
                int kl = kq * 16 + 4 * j;
                wT[(kl + 0) * WTS + f] = v.x;
                wT[(kl + 1) * WTS + f] = v.y;
                wT[(kl + 2) * WTS + f] = v.z;
                wT[(kl + 3) * WTS + f] = v.w;
            }
        }
        {
            int n = t & 127, half = t >> 7;
            int node = node0 + n;
#pragma unroll
            for (int j = 0; j < 8; j++) {
                int ku = half * 8 + j;
                float4 v = make_float4(0.f, 0.f, 0.f, 0.f);
                if (node < N_NODES)
                    v = *(const float4*)&x[(size_t)node * F_IN + k0 + 4 * ku];
                int kl = 4 * ku;
                xT[(kl + 0) * NTB + n] = v.x;
                xT[(kl + 1) * NTB + n] = v.y;
                xT[(kl + 2) * NTB + n] = v.z;
                xT[(kl + 3) * NTB + n] = v.w;
            }
        }
        __syncthreads();
#pragma unroll 8
        for (int k = 0; k < KT; k++) {
            float4 wf = *(const float4*)&wT[k * WTS + fi * 4];
            float4 xa = *(const float4*)&xT[k * NTB + n0];
            float4 xb = *(const float4*)&xT[k * NTB + n0 + 4];
            float wr[4] = {wf.x, wf.y, wf.z, wf.w};
            float xv[8] = {xa.x, xa.y, xa.z, xa.w, xb.x, xb.y, xb.z, xb.w};
#pragma unroll
            for (int r = 0; r < 4; r++)
#pragma unroll
                for (int c = 0; c < 8; c++) acc[r][c] += wr[r] * xv[c];
        }
    }
#pragma unroll
    for (int c = 0; c < 8; c++) {
        int node = node0 + n0 + c;
        if (node < N_NODES) {
            float dv = dinv[node];
            __half2 h0 = __floats2half2_rn(acc[0][c] * dv, acc[1][c] * dv);
            __half2 h1 = __floats2half2_rn(acc[2][c] * dv, acc[3][c] * dv);
            __half2* p = (__half2*)&hs[(size_t)node * F_H + fi * 4];
            p[0] = h0; p[1] = h1;
        }
    }
}

// ---------------------------------------------------------------------------
// Aggregate L1 + relu + wc2 projection — bucket-owned LDS accumulators.
// One block per dst-bucket (1/CU, all 256 start in sync). Edges are sorted
// by src-chunk, so all blocks sweep hs[] in the same ascending order ->
// per-XCD L2 turns the random gather into a near-sequential stream
// (hs fetched ~once per XCD instead of once per edge).
// Half-wave per edge: lanes 0-31 even edge, 32-63 odd edge; lane fp holds
// feature pair (2fp, 2fp+1); accumulate de-interleaved (x at [dl*64+fp],
// y at [dl*64+32+fp]) so ds_add_f32 is a free 2-way bank pattern.
// ---------------------------------------------------------------------------
#define AGG_T 1024
__global__ __launch_bounds__(AGG_T) void k_agg1(const int* __restrict__ bbase,
                                                const int* __restrict__ epk,
                                                const __half* __restrict__ hs,
                                                const float* __restrict__ dinv,
                                                const float* __restrict__ b1,
                                                const float* __restrict__ wc2,
                                                float* __restrict__ q) {
    __shared__ float acc[NPB * 64];    // 100 KB
    int b = blockIdx.x;
    int t = threadIdx.x;
    int node0 = b * NPB;
    int nloc = min(NPB, N_NODES - node0);
    int beg = bbase[b], end = bbase[b + 1];
    for (int i = t; i < NPB * 64; i += AGG_T) acc[i] = 0.0f;
    __syncthreads();

    int lane = t & 63, wv = t >> 6;    // 16 waves
    int up = lane >> 5, fp = lane & 31;
    const __half2* hs2 = (const __half2*)hs;
    const int SMASK = (1 << SRC_BITS) - 1;

#define AGG_BODY(IDX)                                                    \
    {                                                                    \
        int pe = __shfl(pk, (IDX), 64);                                  \
        int sn = pe & SMASK;                                             \
        int dl = pe >> SRC_BITS;                                         \
        float2 v = __half22float2(hs2[sn * 32 + fp]);                    \
        atomicAdd(&acc[dl * 64 + fp], v.x);                              \
        atomicAdd(&acc[dl * 64 + 32 + fp], v.y);                         \
    }

    for (int base = beg + wv * 64; base < end; base += AGG_T) {
        int navail = end - base;
        int pk = 0;
        if (lane < navail) pk = epk[base + lane];
        if (navail >= 64) {
#pragma unroll 8
            for (int u = 0; u < 32; u++) AGG_BODY(2 * u + up)
        } else {
            int npair = navail >> 1;
            for (int u = 0; u < npair; u++) AGG_BODY(2 * u + up)
            if ((navail & 1) && up == 0) AGG_BODY(navail - 1)
        }
    }
    __syncthreads();

    // epilogue: each half-wave finishes one node; 32 node-slots per pass
    for (int i = wv * 2 + up; i < nloc; i += 32) {
        int node = node0 + i;
        float ax = acc[i * 64 + fp];
        float ay = acc[i * 64 + 32 + fp];
        float2 s = __half22float2(hs2[(size_t)node * 32 + fp]);
        float dv = dinv[node];
        float2 bb = *(const float2*)&b1[2 * fp];
        float2 ww = *(const float2*)&wc2[2 * fp];
        float z0 = fmaxf(fmaf(dv, ax + s.x, bb.x), 0.0f);
        float z1 = fmaxf(fmaf(dv, ay + s.y, bb.y), 0.0f);
        float p = z0 * ww.x + z1 * ww.y;
#pragma unroll
        for (int off = 1; off < 32; off <<= 1)
            p += __shfl_xor(p, off, 64);
        if (fp == 0) q[node] = dv * p;
    }
#undef AGG_BODY
}

// ---------------------------------------------------------------------------
// Final: out[d] = dinv[d] * (q[d] + sum_{s->d} q[s]) + c0
// Same bucket structure; scalar LDS accumulators (1.6 KB). q is L2-resident.
// ---------------------------------------------------------------------------
#define KF_T 512
__global__ __launch_bounds__(KF_T) void k_final(const int* __restrict__ bbase,
                                                const int* __restrict__ epk,
                                                const float* __restrict__ qv,
                                                const float* __restrict__ dinv,
                                                const float* __restrict__ c0,
                                                float* __restrict__ out) {
    __shared__ float accq[NPB];
    int b = blockIdx.x, t = threadIdx.x;
    int node0 = b * NPB;
    int nloc = min(NPB, N_NODES - node0);
    int beg = bbase[b], end = bbase[b + 1];
    for (int i = t; i < NPB; i += KF_T) accq[i] = 0.0f;
    __syncthreads();
    const int SMASK = (1 << SRC_BITS) - 1;
    int j = beg + t;
    for (; j + 3 * KF_T < end; j += 4 * KF_T) {
        int p0 = epk[j], p1 = epk[j + KF_T], p2 = epk[j + 2 * KF_T], p3 = epk[j + 3 * KF_T];
        float a0 = qv[p0 & SMASK], a1 = qv[p1 & SMASK];
        float a2 = qv[p2 & SMASK], a3 = qv[p3 & SMASK];
        atomicAdd(&accq[p0 >> SRC_BITS], a0);
        atomicAdd(&accq[p1 >> SRC_BITS], a1);
        atomicAdd(&accq[p2 >> SRC_BITS], a2);
        atomicAdd(&accq[p3 >> SRC_BITS], a3);
    }
    for (; j < end; j += KF_T) {
        int p = epk[j];
        atomicAdd(&accq[p >> SRC_BITS], qv[p & SMASK]);
    }
    __syncthreads();
    for (int i = t; i < nloc; i += KF_T) {
        int node = node0 + i;
        out[node] = dinv[node] * (qv[node] + accq[i]) + c0[0];
    }
}

// ---------------------------------------------------------------------------
extern "C" void kernel_launch(void* const* d_in, const int* in_sizes, int n_in,
                              void* d_out, int out_size, void* d_ws, size_t ws_size,
                              hipStream_t stream) {
    const float* x  = (const float*)d_in[0];
    const int*   ei = (const int*)d_in[1];
    const int*   src = ei;
    const int*   dst = ei + N_EDGES;
    const float* W1 = (const float*)d_in[2];
    const float* b1 = (const float*)d_in[3];
    const float* W2 = (const float*)d_in[4];
    const float* b2 = (const float*)d_in[5];
    const float* Wc = (const float*)d_in[6];
    const float* bc = (const float*)d_in[7];
    float* out = (float*)d_out;

    char* w = (char*)d_ws;
    int*    bcount  = (int*)w;    w += NBUCK * 4;
    int*    bbase   = (int*)w;    w += (NBUCK + 1) * 4;
    int*    bcur    = (int*)w;    w += NBUCK * 4;
    float*  wc2     = (float*)w;  w += 64 * 4;
    float*  c0      = (float*)w;  w += 4 * 4;
    float*  dinv    = (float*)w;  w += (size_t)N_NODES * 4;
    float*  q       = (float*)w;  w += (size_t)N_NODES * 4;
    int*    epk     = (int*)w;    w += (size_t)N_EDGES * 4;        // chunk-sorted packed edges
    __half* bufA    = (__half*)w; w += (size_t)N_NODES * F_H * 2;  // hs1 (12.8 MB)
    int*    packT   = (int*)w;    w += (size_t)N_EDGES * 4;        // sort intermediate

    const int NB_BH = (int)(((long long)N_EDGES + BH_C - 1) / BH_C);  // 196
    const int NB_PA = (int)(((long long)N_EDGES + PA_C - 1) / PA_C);  // 782
    const int NB_G  = (N_NODES + NTB - 1) / NTB;                      // 782

    hipMemsetAsync(bcount, 0, NBUCK * 4, stream);
    k_bhist<<<NB_BH, BH_T, 0, stream>>>(dst, bcount);
    k_bscan<<<1, NBUCK, 0, stream>>>(bcount, bbase, bcur);
    k_wc2  <<<1, 64, 0, stream>>>(W2, Wc, b2, bc, wc2, c0);
    k_partA<<<NB_PA, PA_T, 0, stream>>>(src, dst, bcur, packT);
    k_partB<<<NBUCK, PB_T, 0, stream>>>(bbase, packT, dinv, epk);

    // layer 1: gemm -> hs fp16; bucket-LDS aggregate + relu + project -> q
    k_gemm1<<<NB_G, GT, 0, stream>>>(x, W1, dinv, bufA);
    k_agg1 <<<NBUCK, AGG_T, 0, stream>>>(bbase, epk, bufA, dinv, b1, wc2, q);

    // collapsed layer 2 + head: bucket-LDS scalar aggregate over q
    k_final<<<NBUCK, KF_T, 0, stream>>>(bbase, epk, q, dinv, c0, out);
}

// Round 3
// 396.721 us; speedup vs baseline: 3.2126x; 3.2126x over previous
//
#include <hip/hip_runtime.h>
#include <hip/hip_bf16.h>
#include <hip/hip_fp16.h>

#define N_NODES 100000
#define N_EDGES 3200000
#define F_IN    128
#define F_H     64

#define NBUCK 256
#define NPB   391            // ceil(N_NODES / NBUCK); last bucket short
#define SRC_BITS 17          // N_NODES < 2^17; pack = (dstLocal<<17)|src
#define CH2_SHIFT 14         // src-chunk = src>>14 (16384 nodes = 2 MB of hs)
#define NCH2 7               // ceil(100000/16384)
#define NBINS (NPB * NCH2)   // 2737 combined (dstLocal, chunk) bins

// ---------------------------------------------------------------------------
// Bucket-level histogram: 256 bins, LDS-aggregated
// ---------------------------------------------------------------------------
#define BH_T 256
#define BH_C 16384           // edges per block -> 196 blocks
__global__ __launch_bounds__(BH_T) void k_bhist(const int* __restrict__ dst,
                                                int* __restrict__ bcount) {
    __shared__ int lc[NBUCK];
    int t = threadIdx.x;
    lc[t] = 0;
    __syncthreads();
    long long e0 = (long long)blockIdx.x * BH_C;
    long long e1 = e0 + BH_C; if (e1 > N_EDGES) e1 = N_EDGES;
    for (long long e = e0 + t; e < e1; e += BH_T)
        atomicAdd(&lc[dst[e] / NPB], 1);
    __syncthreads();
    int c = lc[t];
    if (c) atomicAdd(&bcount[t], c);
}

// ---------------------------------------------------------------------------
// Scan of 256 bucket counts -> bucket bases + partA cursors
// ---------------------------------------------------------------------------
__global__ __launch_bounds__(NBUCK) void k_bscan(const int* __restrict__ bcount,
                                                 int* __restrict__ bbase,
                                                 int* __restrict__ bcur) {
    __shared__ int s[NBUCK];
    int t = threadIdx.x;
    int c = bcount[t];
    s[t] = c;
    __syncthreads();
    for (int off = 1; off < NBUCK; off <<= 1) {
        int v = (t >= off) ? s[t - off] : 0;
        __syncthreads();
        s[t] += v;
        __syncthreads();
    }
    int ex = s[t] - c;
    bbase[t] = ex;
    bcur[t]  = ex;
    if (t == NBUCK - 1) bbase[NBUCK] = s[t];   // = N_EDGES
}

// ---------------------------------------------------------------------------
// wc2 = W2^T Wc (64-vector), c0 = Wc.b2 + bc  — collapses layer2+head
// ---------------------------------------------------------------------------
__global__ __launch_bounds__(64) void k_wc2(const float* __restrict__ W2,
                                            const float* __restrict__ Wc,
                                            const float* __restrict__ b2,
                                            const float* __restrict__ bc,
                                            float* __restrict__ wc2,
                                            float* __restrict__ c0) {
    int k = threadIdx.x;
    float s = 0.0f;
#pragma unroll 8
    for (int f = 0; f < F_H; f++) s += Wc[f] * W2[f * F_H + k];
    wc2[k] = s;
    float p = Wc[k] * b2[k];
#pragma unroll
    for (int off = 32; off > 0; off >>= 1) p += __shfl_xor(p, off, 64);
    if (k == 0) c0[0] = p + bc[0];
}

// ---------------------------------------------------------------------------
// Pass A: partition edges into NBUCK dst-range buckets; emit packed
// (dstLocal<<17)|src words (LDS-staged, coalesced out)
// ---------------------------------------------------------------------------
#define PA_T   256
#define PA_C   4096
#define PA_PER (PA_C / PA_T)   // 16
__global__ __launch_bounds__(PA_T) void k_partA(const int* __restrict__ src,
                                                const int* __restrict__ dst,
                                                int* __restrict__ bucket_cursor,
                                                int* __restrict__ packT) {
    __shared__ int lcount[NBUCK];
    __shared__ int lstart[NBUCK];
    __shared__ int loffs[NBUCK];
    __shared__ int lbase[NBUCK];
    __shared__ int s_pack[PA_C];
    __shared__ unsigned char s_bkt[PA_C];
    __shared__ int ltot;
    int t = threadIdx.x;
    long long e0 = (long long)blockIdx.x * PA_C;
    if (t < NBUCK) lcount[t] = 0;
    __syncthreads();
    int ep[PA_PER];
    short eb[PA_PER];
#pragma unroll
    for (int i = 0; i < PA_PER; i++) {
        long long e = e0 + i * PA_T + t;
        if (e < N_EDGES) {
            int es = src[e], ed = dst[e];
            int b = ed / NPB;
            eb[i] = (short)b;
            ep[i] = ((ed - b * NPB) << SRC_BITS) | es;
            atomicAdd(&lcount[b], 1);
        } else eb[i] = -1;
    }
    __syncthreads();
    // exclusive scan of lcount (256) by wave 0: 4 serial/lane + shfl scan
    if (t < 64) {
        int base = t * 4;
        int c0 = lcount[base], c1 = lcount[base + 1], c2 = lcount[base + 2], c3 = lcount[base + 3];
        int ssum = c0 + c1 + c2 + c3;
        int sc = ssum;
#pragma unroll
        for (int off = 1; off < 64; off <<= 1) {
            int v = __shfl_up(sc, off, 64);
            if (t >= off) sc += v;
        }
        int ex = sc - ssum;
        lstart[base]     = ex;
        lstart[base + 1] = ex + c0;
        lstart[base + 2] = ex + c0 + c1;
        lstart[base + 3] = ex + c0 + c1 + c2;
        if (t == 63) ltot = sc;
    }
    __syncthreads();
    if (t < NBUCK) {
        loffs[t] = lstart[t];
        int c = lcount[t];
        lbase[t] = c ? atomicAdd(&bucket_cursor[t], c) : 0;
    }
    __syncthreads();
#pragma unroll
    for (int i = 0; i < PA_PER; i++) {
        if (eb[i] >= 0) {
            int idx = atomicAdd(&loffs[eb[i]], 1);
            s_pack[idx] = ep[i];
            s_bkt[idx] = (unsigned char)eb[i];
        }
    }
    __syncthreads();
    int tot = ltot;
    for (int i = t; i < tot; i += PA_T) {
        int b = s_bkt[i];
        int addr = lbase[b] + (i - lstart[b]);
        packT[addr] = s_pack[i];
    }
}

// ---------------------------------------------------------------------------
// Pass B: per-bucket counting sort by combined key (dstLocal, src_chunk).
// Produces srcs[] grouped by dst, chunk-ascending within each dst, plus
// rowptr2[node][8]: per-node per-chunk segment boundaries, and dinv[node].
// ---------------------------------------------------------------------------
#define PB_T   1024
#define PB_CAP 16384
__global__ __launch_bounds__(PB_T) void k_partB(const int* __restrict__ bbase,
                                                const int* __restrict__ packT,
                                                float* __restrict__ dinv,
                                                int* __restrict__ srcs,
                                                int* __restrict__ rowptr2) {
    __shared__ int hist[NBINS];        // counts -> exclusive prefix -> cursors
    __shared__ int s_out[PB_CAP];
    __shared__ int wsum[16];
    int b = blockIdx.x;
    int node0 = b * NPB;
    int nloc = min(NPB, N_NODES - node0);
    int beg = bbase[b];
    int end = bbase[b + 1];
    int len = end - beg;
    int t = threadIdx.x;
    int lane = t & 63, wv = t >> 6;
    const int SMASK = (1 << SRC_BITS) - 1;

    for (int i = t; i < NBINS; i += PB_T) hist[i] = 0;
    __syncthreads();
    for (int i = t; i < len; i += PB_T) {
        int pk = packT[beg + i];
        int bin = (pk >> SRC_BITS) * NCH2 + ((pk & SMASK) >> CH2_SHIFT);
        atomicAdd(&hist[bin], 1);
    }
    __syncthreads();
    // exclusive scan of NBINS=2737 bins: 3 serial/thread + block scan
    int t3 = t * 3;
    int c0 = (t3     < NBINS) ? hist[t3]     : 0;
    int c1 = (t3 + 1 < NBINS) ? hist[t3 + 1] : 0;
    int c2 = (t3 + 2 < NBINS) ? hist[t3 + 2] : 0;
    int ssum = c0 + c1 + c2;
    int sc = ssum;
#pragma unroll
    for (int off = 1; off < 64; off <<= 1) {
        int v = __shfl_up(sc, off, 64);
        if (lane >= off) sc += v;
    }
    if (lane == 63) wsum[wv] = sc;
    __syncthreads();
    if (t < 16) {
        int w = wsum[t];
        int sw = w;
#pragma unroll
        for (int off = 1; off < 16; off <<= 1) {
            int v = __shfl_up(sw, off, 16);
            if (t >= off) sw += v;
        }
        wsum[t] = sw - w;     // exclusive wave base
    }
    __syncthreads();
    int run = (sc - ssum) + wsum[wv];
    if (t3 < NBINS)     { int x = hist[t3];     hist[t3]     = run; run += x; }
    if (t3 + 1 < NBINS) { int x = hist[t3 + 1]; hist[t3 + 1] = run; run += x; }
    if (t3 + 2 < NBINS) { int x = hist[t3 + 2]; hist[t3 + 2] = run; run += x; }
    __syncthreads();
    // rowptr2 / dinv from exclusive prefixes (before scatter mutates hist)
    for (int i = t; i < nloc; i += PB_T) {
        int p0 = hist[i * NCH2];
        int e7 = (i == nloc - 1) ? len : hist[(i + 1) * NCH2];
        dinv[node0 + i] = rsqrtf((float)(e7 - p0 + 1));
        int* rp = &rowptr2[(size_t)(node0 + i) * 8];
#pragma unroll
        for (int c = 0; c < NCH2; c++) rp[c] = beg + hist[i * NCH2 + c];
        rp[7] = beg + e7;
    }
    __syncthreads();
    if (len <= PB_CAP) {
        for (int i = t; i < len; i += PB_T) {
            int pk = packT[beg + i];
            int sn = pk & SMASK;
            int bin = (pk >> SRC_BITS) * NCH2 + (sn >> CH2_SHIFT);
            int idx = atomicAdd(&hist[bin], 1);
            s_out[idx] = sn;
        }
        __syncthreads();
        for (int i = t; i < len; i += PB_T)
            srcs[beg + i] = s_out[i];
    } else {    // statistically never (>30 sigma): direct global scatter
        for (int i = t; i < len; i += PB_T) {
            int pk = packT[beg + i];
            int sn = pk & SMASK;
            int bin = (pk >> SRC_BITS) * NCH2 + (sn >> CH2_SHIFT);
            int idx = atomicAdd(&hist[bin], 1);
            srcs[beg + idx] = sn;
        }
    }
}

// ---------------------------------------------------------------------------
// Layer-1 GEMM: hs16 = fp16( (x @ W1^T) * dinv )
// ---------------------------------------------------------------------------
#define GT   256
#define NTB  128     // nodes per block
#define KT   64      // k-tile (2 passes for F_IN=128)
#define WTS  68      // wT stride (words)

__global__ __launch_bounds__(GT) void k_gemm1(const float* __restrict__ x,
                                              const float* __restrict__ W1,
                                              const float* __restrict__ dinv,
                                              __half* __restrict__ hs) {
    __shared__ float wT[KT * WTS];     // 17.4 KB
    __shared__ float xT[KT * NTB];     // 32 KB
    int t = threadIdx.x;
    int node0 = blockIdx.x * NTB;
    int lane = t & 63, wv = t >> 6;
    int fi = lane & 15, ni = lane >> 4;
    int n0 = wv * 32 + ni * 8;

    float acc[4][8];
#pragma unroll
    for (int r = 0; r < 4; r++)
#pragma unroll
        for (int c = 0; c < 8; c++) acc[r][c] = 0.0f;

    for (int p = 0; p < 2; p++) {
        int k0 = p * KT;
        if (p) __syncthreads();
        {
            int f = t & 63, kq = t >> 6;
            const float4* wp = (const float4*)&W1[(size_t)f * F_IN + k0 + kq * 16];
#pragma unroll
            for (int j = 0; j < 4; j++) {
                float4 v = wp[j];
                int kl = kq * 16 + 4 * j;
                wT[(kl + 0) * WTS + f] = v.x;
                wT[(kl + 1) * WTS + f] = v.y;
                wT[(kl + 2) * WTS + f] = v.z;
                wT[(kl + 3) * WTS + f] = v.w;
            }
        }
        {
            int n = t & 127, half = t >> 7;
            int node = node0 + n;
#pragma unroll
            for (int j = 0; j < 8; j++) {
                int ku = half * 8 + j;
                float4 v = make_float4(0.f, 0.f, 0.f, 0.f);
                if (node < N_NODES)
                    v = *(const float4*)&x[(size_t)node * F_IN + k0 + 4 * ku];
                int kl = 4 * ku;
                xT[(kl + 0) * NTB + n] = v.x;
                xT[(kl + 1) * NTB + n] = v.y;
                xT[(kl + 2) * NTB + n] = v.z;
                xT[(kl + 3) * NTB + n] = v.w;
            }
        }
        __syncthreads();
#pragma unroll 8
        for (int k = 0; k < KT; k++) {
            float4 wf = *(const float4*)&wT[k * WTS + fi * 4];
            float4 xa = *(const float4*)&xT[k * NTB + n0];
            float4 xb = *(const float4*)&xT[k * NTB + n0 + 4];
            float wr[4] = {wf.x, wf.y, wf.z, wf.w};
            float xv[8] = {xa.x, xa.y, xa.z, xa.w, xb.x, xb.y, xb.z, xb.w};
#pragma unroll
            for (int r = 0; r < 4; r++)
#pragma unroll
                for (int c = 0; c < 8; c++) acc[r][c] += wr[r] * xv[c];
        }
    }
#pragma unroll
    for (int c = 0; c < 8; c++) {
        int node = node0 + n0 + c;
        if (node < N_NODES) {
            float dv = dinv[node];
            __half2 h0 = __floats2half2_rn(acc[0][c] * dv, acc[1][c] * dv);
            __half2 h1 = __floats2half2_rn(acc[2][c] * dv, acc[3][c] * dv);
            __half2* p = (__half2*)&hs[(size_t)node * F_H + fi * 4];
            p[0] = h0; p[1] = h1;
        }
    }
}

// ---------------------------------------------------------------------------
// Aggregate L1 + relu + wc2 projection — chunk-lockstep register version.
// Each wave owns APW=13 nodes (13 static __half2 accumulators). Outer loop
// over the 7 src-chunks, inner over the wave's nodes' per-chunk segments.
// Grid = 1924 blocks <= 2048 resident at __launch_bounds__(256,8): ALL waves
// co-resident -> every wave sweeps the same 2 MB hs window concurrently ->
// gathers become L2 hits. No LDS, no atomics, no shfl in the edge path.
// ---------------------------------------------------------------------------
#define APW 13
__global__ __launch_bounds__(256, 8) void k_agg2(const int* __restrict__ srcs,
                                                 const int* __restrict__ rowptr2,
                                                 const __half* __restrict__ hs,
                                                 const float* __restrict__ dinv,
                                                 const float* __restrict__ b1,
                                                 const float* __restrict__ wc2,
                                                 float* __restrict__ q) {
    int t = threadIdx.x;
    int wid = blockIdx.x * 4 + (t >> 6);
    int nb = wid * APW;
    if (nb >= N_NODES) return;
    int lane = t & 63;
    int up = lane >> 5, fp = lane & 31;
    const __half2* hs2 = (const __half2*)hs;

    __half2 acc[APW];
#pragma unroll
    for (int n = 0; n < APW; n++) {
        int node = nb + n;
        acc[n] = (up == 0 && node < N_NODES) ? hs2[node * 32 + fp]
                                             : __float2half2_rn(0.0f);
    }

    for (int c = 0; c < NCH2; c++) {
#pragma unroll
        for (int n = 0; n < APW; n++) {
            int node = nb + n;
            if (node < N_NODES) {
                const int* rp = &rowptr2[(size_t)node * 8 + c];
                int jb = rp[0], je = rp[1];
                int j = jb;
                for (; j + 2 <= je; j += 2) {
                    int sel = up ? srcs[j + 1] : srcs[j];
                    acc[n] = __hadd2(acc[n], hs2[sel * 32 + fp]);
                }
                if (j < je && up == 0)
                    acc[n] = __hadd2(acc[n], hs2[srcs[j] * 32 + fp]);
            }
        }
    }

    // epilogue per node: combine halves, relu + wc2 projection, reduce
#pragma unroll
    for (int n = 0; n < APW; n++) {
        int node = nb + n;
        if (node >= N_NODES) break;
        int ai = *(int*)&acc[n];
        int bi = __shfl_xor(ai, 32, 64);
        __half2 a = __hadd2(acc[n], *(__half2*)&bi);
        float2 a2 = __half22float2(a);
        float dv = dinv[node];
        float2 bb = *(const float2*)&b1[2 * fp];
        float2 ww = *(const float2*)&wc2[2 * fp];
        float z0 = fmaxf(fmaf(dv, a2.x, bb.x), 0.0f);
        float z1 = fmaxf(fmaf(dv, a2.y, bb.y), 0.0f);
        float p = z0 * ww.x + z1 * ww.y;
#pragma unroll
        for (int off = 16; off > 0; off >>= 1)
            p += __shfl_xor(p, off, 64);
        if (lane == 0) q[node] = dv * p;
    }
}

// ---------------------------------------------------------------------------
// Final: out[d] = dinv[d] * (q[d] + sum_{s->d} q[s]) + c0
// one thread per node; q (400 KB) is L2-resident
// ---------------------------------------------------------------------------
__global__ void k_final(const int* __restrict__ rowptr2, const int* __restrict__ srcs,
                        const float* __restrict__ q, const float* __restrict__ dinv,
                        const float* __restrict__ c0, float* __restrict__ out) {
    int node = blockIdx.x * blockDim.x + threadIdx.x;
    if (node >= N_NODES) return;
    int beg = rowptr2[(size_t)node * 8];
    int end = rowptr2[(size_t)node * 8 + 7];
    float acc = q[node];
    int j = beg;
    for (; j + 4 <= end; j += 4) {
        int s0 = srcs[j], s1 = srcs[j + 1], s2 = srcs[j + 2], s3 = srcs[j + 3];
        float a0 = q[s0], a1 = q[s1], a2 = q[s2], a3 = q[s3];
        acc += (a0 + a1) + (a2 + a3);
    }
    for (; j < end; j++) acc += q[srcs[j]];
    out[node] = dinv[node] * acc + c0[0];
}

// ---------------------------------------------------------------------------
extern "C" void kernel_launch(void* const* d_in, const int* in_sizes, int n_in,
                              void* d_out, int out_size, void* d_ws, size_t ws_size,
                              hipStream_t stream) {
    const float* x  = (const float*)d_in[0];
    const int*   ei = (const int*)d_in[1];
    const int*   src = ei;
    const int*   dst = ei + N_EDGES;
    const float* W1 = (const float*)d_in[2];
    const float* b1 = (const float*)d_in[3];
    const float* W2 = (const float*)d_in[4];
    const float* b2 = (const float*)d_in[5];
    const float* Wc = (const float*)d_in[6];
    const float* bc = (const float*)d_in[7];
    float* out = (float*)d_out;

    char* w = (char*)d_ws;
    int*    bcount  = (int*)w;    w += NBUCK * 4;
    int*    bbase   = (int*)w;    w += (NBUCK + 1) * 4;
    int*    bcur    = (int*)w;    w += NBUCK * 4;
    float*  wc2     = (float*)w;  w += 64 * 4;
    float*  c0      = (float*)w;  w += 4 * 4;
    float*  dinv    = (float*)w;  w += (size_t)N_NODES * 4;
    float*  q       = (float*)w;  w += (size_t)N_NODES * 4;
    int*    rowptr2 = (int*)w;    w += (size_t)N_NODES * 8 * 4;    // 3.2 MB
    int*    srcs    = (int*)w;    w += (size_t)N_EDGES * 4;
    __half* bufA    = (__half*)w; w += (size_t)N_NODES * F_H * 2;  // hs1 (12.8 MB)
    int*    packT   = (int*)w;    w += (size_t)N_EDGES * 4;        // sort intermediate

    const int TB = 256;
    const int NB_BH = (int)(((long long)N_EDGES + BH_C - 1) / BH_C);  // 196
    const int NB_PA = (int)(((long long)N_EDGES + PA_C - 1) / PA_C);  // 782
    const int NB_G  = (N_NODES + NTB - 1) / NTB;                      // 782
    const int NWAVE = (N_NODES + APW - 1) / APW;                      // 7693
    const int NB_AG = (NWAVE + 3) / 4;                                // 1924

    hipMemsetAsync(bcount, 0, NBUCK * 4, stream);
    k_bhist<<<NB_BH, BH_T, 0, stream>>>(dst, bcount);
    k_bscan<<<1, NBUCK, 0, stream>>>(bcount, bbase, bcur);
    k_wc2  <<<1, 64, 0, stream>>>(W2, Wc, b2, bc, wc2, c0);
    k_partA<<<NB_PA, PA_T, 0, stream>>>(src, dst, bcur, packT);
    k_partB<<<NBUCK, PB_T, 0, stream>>>(bbase, packT, dinv, srcs, rowptr2);

    // layer 1: gemm -> hs fp16; chunk-lockstep register aggregate -> q
    k_gemm1<<<NB_G, GT, 0, stream>>>(x, W1, dinv, bufA);
    k_agg2 <<<NB_AG, 256, 0, stream>>>(srcs, rowptr2, bufA, dinv, b1, wc2, q);

    // collapsed layer 2 + head: scalar gather over q
    k_final<<<(N_NODES + TB - 1) / TB, TB, 0, stream>>>(rowptr2, srcs, q, dinv, c0, out);
}

// Round 4
// 395.787 us; speedup vs baseline: 3.2202x; 1.0024x over previous
//
#include <hip/hip_runtime.h>
#include <hip/hip_bf16.h>
#include <hip/hip_fp16.h>

#define N_NODES 100000
#define N_EDGES 3200000
#define F_IN    128
#define F_H     64

#define NBUCK 256
#define NPB   391            // ceil(N_NODES / NBUCK) = 23 * 17
#define SRC_BITS 17          // N_NODES < 2^17; pack = (id<<17)|src
#define CH2_SHIFT 14         // src-chunk = src>>14 (16384 nodes = 2 MB of hs)
#define NCH2 7               // ceil(100000/16384)
#define APW   17             // nodes per wave
#define WPBK  23             // waves per bucket (17*23 = 391)
#define NRUN  (WPBK * NCH2)  // 161 runs per bucket
#define NBINS2 (NRUN * APW)  // 2737 bins: ((w*7 + c)*17 + nl)
#define BCAP  16384          // padded per-bucket capacity (24 sigma headroom)
#define NWAVES (NBUCK * WPBK) // 5888
#define SENT  ((16 << SRC_BITS) | N_NODES)   // sentinel: node-slot 16, zero row

// ---------------------------------------------------------------------------
// Bucket-level histogram: 256 bins, LDS-aggregated
// ---------------------------------------------------------------------------
#define BH_T 256
#define BH_C 16384           // edges per block -> 196 blocks
__global__ __launch_bounds__(BH_T) void k_bhist(const int* __restrict__ dst,
                                                int* __restrict__ bcount) {
    __shared__ int lc[NBUCK];
    int t = threadIdx.x;
    lc[t] = 0;
    __syncthreads();
    long long e0 = (long long)blockIdx.x * BH_C;
    long long e1 = e0 + BH_C; if (e1 > N_EDGES) e1 = N_EDGES;
    for (long long e = e0 + t; e < e1; e += BH_T)
        atomicAdd(&lc[dst[e] / NPB], 1);
    __syncthreads();
    int c = lc[t];
    if (c) atomicAdd(&bcount[t], c);
}

// ---------------------------------------------------------------------------
// Scan of 256 bucket counts -> bucket bases + partA cursors
// ---------------------------------------------------------------------------
__global__ __launch_bounds__(NBUCK) void k_bscan(const int* __restrict__ bcount,
                                                 int* __restrict__ bbase,
                                                 int* __restrict__ bcur) {
    __shared__ int s[NBUCK];
    int t = threadIdx.x;
    int c = bcount[t];
    s[t] = c;
    __syncthreads();
    for (int off = 1; off < NBUCK; off <<= 1) {
        int v = (t >= off) ? s[t - off] : 0;
        __syncthreads();
        s[t] += v;
        __syncthreads();
    }
    int ex = s[t] - c;
    bbase[t] = ex;
    bcur[t]  = ex;
    if (t == NBUCK - 1) bbase[NBUCK] = s[t];   // = N_EDGES
}

// ---------------------------------------------------------------------------
// wc2 = W2^T Wc (64-vector), c0 = Wc.b2 + bc; also zeroes q[N_NODES]
// ---------------------------------------------------------------------------
__global__ __launch_bounds__(64) void k_wc2(const float* __restrict__ W2,
                                            const float* __restrict__ Wc,
                                            const float* __restrict__ b2,
                                            const float* __restrict__ bc,
                                            float* __restrict__ wc2,
                                            float* __restrict__ c0,
                                            float* __restrict__ q) {
    int k = threadIdx.x;
    float s = 0.0f;
#pragma unroll 8
    for (int f = 0; f < F_H; f++) s += Wc[f] * W2[f * F_H + k];
    wc2[k] = s;
    float p = Wc[k] * b2[k];
#pragma unroll
    for (int off = 32; off > 0; off >>= 1) p += __shfl_xor(p, off, 64);
    if (k == 0) { c0[0] = p + bc[0]; q[N_NODES] = 0.0f; }
}

// ---------------------------------------------------------------------------
// Pass A: partition edges into NBUCK dst-range buckets; emit packed
// (dstLocal<<17)|src words (LDS-staged, coalesced out)
// ---------------------------------------------------------------------------
#define PA_T   256
#define PA_C   4096
#define PA_PER (PA_C / PA_T)   // 16
__global__ __launch_bounds__(PA_T) void k_partA(const int* __restrict__ src,
                                                const int* __restrict__ dst,
                                                int* __restrict__ bucket_cursor,
                                                int* __restrict__ packT) {
    __shared__ int lcount[NBUCK];
    __shared__ int lstart[NBUCK];
    __shared__ int loffs[NBUCK];
    __shared__ int lbase[NBUCK];
    __shared__ int s_pack[PA_C];
    __shared__ unsigned char s_bkt[PA_C];
    __shared__ int ltot;
    int t = threadIdx.x;
    long long e0 = (long long)blockIdx.x * PA_C;
    if (t < NBUCK) lcount[t] = 0;
    __syncthreads();
    int ep[PA_PER];
    short eb[PA_PER];
#pragma unroll
    for (int i = 0; i < PA_PER; i++) {
        long long e = e0 + i * PA_T + t;
        if (e < N_EDGES) {
            int es = src[e], ed = dst[e];
            int b = ed / NPB;
            eb[i] = (short)b;
            ep[i] = ((ed - b * NPB) << SRC_BITS) | es;
            atomicAdd(&lcount[b], 1);
        } else eb[i] = -1;
    }
    __syncthreads();
    // exclusive scan of lcount (256) by wave 0: 4 serial/lane + shfl scan
    if (t < 64) {
        int base = t * 4;
        int c0 = lcount[base], c1 = lcount[base + 1], c2 = lcount[base + 2], c3 = lcount[base + 3];
        int ssum = c0 + c1 + c2 + c3;
        int sc = ssum;
#pragma unroll
        for (int off = 1; off < 64; off <<= 1) {
            int v = __shfl_up(sc, off, 64);
            if (t >= off) sc += v;
        }
        int ex = sc - ssum;
        lstart[base]     = ex;
        lstart[base + 1] = ex + c0;
        lstart[base + 2] = ex + c0 + c1;
        lstart[base + 3] = ex + c0 + c1 + c2;
        if (t == 63) ltot = sc;
    }
    __syncthreads();
    if (t < NBUCK) {
        loffs[t] = lstart[t];
        int c = lcount[t];
        lbase[t] = c ? atomicAdd(&bucket_cursor[t], c) : 0;
    }
    __syncthreads();
#pragma unroll
    for (int i = 0; i < PA_PER; i++) {
        if (eb[i] >= 0) {
            int idx = atomicAdd(&loffs[eb[i]], 1);
            s_pack[idx] = ep[i];
            s_bkt[idx] = (unsigned char)eb[i];
        }
    }
    __syncthreads();
    int tot = ltot;
    for (int i = t; i < tot; i += PA_T) {
        int b = s_bkt[i];
        int addr = lbase[b] + (i - lstart[b]);
        packT[addr] = s_pack[i];
    }
}

// ---------------------------------------------------------------------------
// Pass B: per-bucket counting sort by (wave, chunk, nodeLocal). Each wave's
// edges become ONE contiguous region (chunk-ascending -> hs-sweep locality;
// node-grouped within chunk -> cheap routing). Runs padded to x16 with
// sentinel words (zero-row gathers). Outputs wrg[wave] = {beg, end}, dinv.
// ---------------------------------------------------------------------------
#define PB_T   1024
__global__ __launch_bounds__(PB_T) void k_partB(const int* __restrict__ bbase,
                                                const int* __restrict__ packT,
                                                float* __restrict__ dinv,
                                                int* __restrict__ epk2,
                                                int* __restrict__ wrg) {
    __shared__ int hist[NBINS2];
    __shared__ int bcur2[NBINS2];
    __shared__ int runL[NRUN];
    __shared__ int runR[NRUN];
    int b = blockIdx.x;
    int beg = bbase[b], end = bbase[b + 1], len = end - beg;
    int t = threadIdx.x;
    int base = b * BCAP;
    const int SMASK = (1 << SRC_BITS) - 1;

    for (int i = t; i < NBINS2; i += PB_T) hist[i] = 0;
    __syncthreads();
    for (int i = t; i < len; i += PB_T) {
        int pk = packT[beg + i];
        int dl = pk >> SRC_BITS;
        int sn = pk & SMASK;
        int c  = sn >> CH2_SHIFT;
        int w  = dl / APW;
        int nl = dl - w * APW;
        atomicAdd(&hist[(w * NCH2 + c) * APW + nl], 1);
    }
    __syncthreads();
    // per-run totals (161 runs)
    if (t < NRUN) {
        int L = 0;
#pragma unroll
        for (int k = 0; k < APW; k++) L += hist[t * APW + k];
        runL[t] = L;
    }
    __syncthreads();
    // exclusive scan of padded (x16) run lengths: wave 0, 3 runs/lane
    if (t < 64) {
        int r0 = t * 3, r1 = r0 + 1, r2 = r0 + 2;
        int p0 = (r0 < NRUN) ? ((runL[r0] + 15) & ~15) : 0;
        int p1 = (r1 < NRUN) ? ((runL[r1] + 15) & ~15) : 0;
        int p2 = (r2 < NRUN) ? ((runL[r2] + 15) & ~15) : 0;
        int ssum = p0 + p1 + p2;
        int sc = ssum;
#pragma unroll
        for (int off = 1; off < 64; off <<= 1) {
            int v = __shfl_up(sc, off, 64);
            if (t >= off) sc += v;
        }
        int ex = sc - ssum;
        if (r0 < NRUN) runR[r0] = ex;
        if (r1 < NRUN) runR[r1] = ex + p0;
        if (r2 < NRUN) runR[r2] = ex + p0 + p1;
    }
    __syncthreads();
    // per-bin cursors within runs + sentinel fill of padding
    if (t < NRUN) {
        int x = runR[t];
#pragma unroll
        for (int k = 0; k < APW; k++) { bcur2[t * APW + k] = x; x += hist[t * APW + k]; }
        int pe = runR[t] + ((runL[t] + 15) & ~15);
        for (int k = x; k < pe; k++) epk2[base + k] = SENT;
    }
    // wave regions
    if (t < WPBK) {
        int gw = b * WPBK + t;
        int last = t * NCH2 + (NCH2 - 1);
        wrg[gw * 2]     = base + runR[t * NCH2];
        wrg[gw * 2 + 1] = base + runR[last] + ((runL[last] + 15) & ~15);
    }
    // dinv from in-degree (+1 self-loop)
    if (t < NPB) {
        int w = t / APW, nl = t - w * APW;
        int deg = 0;
#pragma unroll
        for (int c = 0; c < NCH2; c++) deg += hist[(w * NCH2 + c) * APW + nl];
        int node = b * NPB + t;
        if (node < N_NODES) dinv[node] = rsqrtf((float)(deg + 1));
    }
    __syncthreads();
    // scatter, repacking to (nodeLocal<<17)|src
    for (int i = t; i < len; i += PB_T) {
        int pk = packT[beg + i];
        int dl = pk >> SRC_BITS;
        int sn = pk & SMASK;
        int c  = sn >> CH2_SHIFT;
        int w  = dl / APW;
        int nl = dl - w * APW;
        int pos = atomicAdd(&bcur2[(w * NCH2 + c) * APW + nl], 1);
        epk2[base + pos] = (nl << SRC_BITS) | sn;
    }
}

// ---------------------------------------------------------------------------
// Layer-1 GEMM: hs16 = fp16( (x @ W1^T) * dinv ); also zeroes row N_NODES
// ---------------------------------------------------------------------------
#define GT   256
#define NTB  128     // nodes per block
#define KT   64      // k-tile (2 passes for F_IN=128)
#define WTS  68      // wT stride (words)

__global__ __launch_bounds__(GT) void k_gemm1(const float* __restrict__ x,
                                              const float* __restrict__ W1,
                                              const float* __restrict__ dinv,
                                              __half* __restrict__ hs) {
    __shared__ float wT[KT * WTS];     // 17.4 KB
    __shared__ float xT[KT * NTB];     // 32 KB
    int t = threadIdx.x;
    int node0 = blockIdx.x * NTB;
    int lane = t & 63, wv = t >> 6;
    int fi = lane & 15, ni = lane >> 4;
    int n0 = wv * 32 + ni * 8;

    float acc[4][8];
#pragma unroll
    for (int r = 0; r < 4; r++)
#pragma unroll
        for (int c = 0; c < 8; c++) acc[r][c] = 0.0f;

    for (int p = 0; p < 2; p++) {
        int k0 = p * KT;
        if (p) __syncthreads();
        {
            int f = t & 63, kq = t >> 6;
            const float4* wp = (const float4*)&W1[(size_t)f * F_IN + k0 + kq * 16];
#pragma unroll
            for (int j = 0; j < 4; j++) {
                float4 v = wp[j];
                int kl = kq * 16 + 4 * j;
                wT[(kl + 0) * WTS + f] = v.x;
                wT[(kl + 1) * WTS + f] = v.y;
                wT[(kl + 2) * WTS + f] = v.z;
                wT[(kl + 3) * WTS + f] = v.w;
            }
        }
        {
            int n = t & 127, half = t >> 7;
            int node = node0 + n;
#pragma unroll
            for (int j = 0; j < 8; j++) {
                int ku = half * 8 + j;
                float4 v = make_float4(0.f, 0.f, 0.f, 0.f);
                if (node < N_NODES)
                    v = *(const float4*)&x[(size_t)node * F_IN + k0 + 4 * ku];
                int kl = 4 * ku;
                xT[(kl + 0) * NTB + n] = v.x;
                xT[(kl + 1) * NTB + n] = v.y;
                xT[(kl + 2) * NTB + n] = v.z;
                xT[(kl + 3) * NTB + n] = v.w;
            }
        }
        __syncthreads();
#pragma unroll 8
        for (int k = 0; k < KT; k++) {
            float4 wf = *(const float4*)&wT[k * WTS + fi * 4];
            float4 xa = *(const float4*)&xT[k * NTB + n0];
            float4 xb = *(const float4*)&xT[k * NTB + n0 + 4];
            float wr[4] = {wf.x, wf.y, wf.z, wf.w};
            float xv[8] = {xa.x, xa.y, xa.z, xa.w, xb.x, xb.y, xb.z, xb.w};
#pragma unroll
            for (int r = 0; r < 4; r++)
#pragma unroll
                for (int c = 0; c < 8; c++) acc[r][c] += wr[r] * xv[c];
        }
    }
#pragma unroll
    for (int c = 0; c < 8; c++) {
        int node = node0 + n0 + c;
        if (node < N_NODES) {
            float dv = dinv[node];
            __half2 h0 = __floats2half2_rn(acc[0][c] * dv, acc[1][c] * dv);
            __half2 h1 = __floats2half2_rn(acc[2][c] * dv, acc[3][c] * dv);
            __half2* p = (__half2*)&hs[(size_t)node * F_H + fi * 4];
            p[0] = h0; p[1] = h1;
        } else if (node == N_NODES) {   // sentinel zero row
            __half2 z = __float2half2_rn(0.0f);
            __half2* p = (__half2*)&hs[(size_t)node * F_H + fi * 4];
            p[0] = z; p[1] = z;
        }
    }
}

// ---------------------------------------------------------------------------
// Aggregate L1 + relu + wc2 projection — padded-stream version.
// Wave owns 17 nodes; its edges are one contiguous chunk-ascending region.
// Per 16-edge batch: 16 uniform (scalar-path) word loads, 8 independent
// gathers per half-wave (round-0 MLP), then uniform-branch routing by the
// word's node-id with running-accumulator flush into wave-private LDS
// (plain read-add-write, no atomics, no barriers in the whole kernel).
// ---------------------------------------------------------------------------
__global__ __launch_bounds__(256, 8) void k_agg3(const int* __restrict__ wrg,
                                                 const int* __restrict__ epk2,
                                                 const __half* __restrict__ hs,
                                                 const float* __restrict__ dinv,
                                                 const float* __restrict__ b1,
                                                 const float* __restrict__ wc2,
                                                 float* __restrict__ q) {
    __shared__ __half2 lacc[4 * APW * 64];   // 17.4 KB: [wv][node][up*32+fp]
    int t = threadIdx.x;
    int wv = t >> 6, lane = t & 63;
    int up = lane >> 5, fp = lane & 31;
    int gw = blockIdx.x * 4 + wv;
    // zero own region (wave-exclusive LDS -> no barrier)
    for (int i = lane; i < APW * 64; i += 64)
        lacc[wv * APW * 64 + i] = __float2half2_rn(0.0f);
    int beg  = __builtin_amdgcn_readfirstlane(wrg[gw * 2]);
    int endp = __builtin_amdgcn_readfirstlane(wrg[gw * 2 + 1]);
    const __half2* hs2 = (const __half2*)hs;
    const int SMASK = (1 << SRC_BITS) - 1;
    __half2 acc = __float2half2_rn(0.0f);
    int cur = -1;
    int lbase = wv * APW * 64 + (up << 5) + fp;

    for (int j = beg; j < endp; j += 16) {
        int wd[16];
#pragma unroll
        for (int u = 0; u < 16; u++) wd[u] = epk2[j + u];
        __half2 v[8];
#pragma unroll
        for (int u = 0; u < 8; u++) {
            int sel = wd[2 * u + up] & SMASK;
            v[u] = hs2[sel * 32 + fp];
        }
#pragma unroll
        for (int u = 0; u < 8; u++) {
            int nl0 = wd[2 * u] >> SRC_BITS;
            int nl1 = wd[2 * u + 1] >> SRC_BITS;
            if (nl0 != cur) {                      // uniform branch
                if (cur >= 0) {
                    int ix = lbase + cur * 64;
                    lacc[ix] = __hadd2(lacc[ix], acc);
                }
                acc = __float2half2_rn(0.0f);
                cur = nl0;
            }
            if (nl1 == nl0) {                      // common path
                acc = __hadd2(acc, v[u]);
            } else {                               // mid-pair node change (~11%)
                if (up == 0) acc = __hadd2(acc, v[u]);
                int ix = lbase + cur * 64;
                lacc[ix] = __hadd2(lacc[ix], acc);
                acc = __float2half2_rn(0.0f);
                cur = nl1;
                if (up == 1) acc = __hadd2(acc, v[u]);
            }
        }
    }
    if (cur >= 0) {
        int ix = lbase + cur * 64;
        lacc[ix] = __hadd2(lacc[ix], acc);
    }
    // epilogue: per node combine halves + self-loop, relu + wc2 dot, reduce
#pragma unroll
    for (int n = 0; n < APW; n++) {
        int node = gw * APW + n;
        if (node >= N_NODES) break;
        __half2 lo = lacc[wv * APW * 64 + n * 64 + fp];
        __half2 hi = lacc[wv * APW * 64 + n * 64 + 32 + fp];
        __half2 a = __hadd2(__hadd2(lo, hi), hs2[(size_t)node * 32 + fp]);
        float2 a2 = __half22float2(a);
        float dv = dinv[node];
        float2 bb = *(const float2*)&b1[2 * fp];
        float2 ww = *(const float2*)&wc2[2 * fp];
        float z0 = fmaxf(fmaf(dv, a2.x, bb.x), 0.0f);
        float z1 = fmaxf(fmaf(dv, a2.y, bb.y), 0.0f);
        float p = z0 * ww.x + z1 * ww.y;
#pragma unroll
        for (int off = 16; off > 0; off >>= 1)
            p += __shfl_xor(p, off, 64);
        if (lane == 0) q[node] = dv * p;
    }
}

// ---------------------------------------------------------------------------
// Final: out[d] = dinv[d] * (q[d] + sum_{s->d} q[s]) + c0
// Same padded per-wave region; per-lane coalesced word loads; q gathers hit
// L2 (400 KB); per-wave LDS atomicAdd into 17 scalar slots. q[N_NODES]=0
// absorbs sentinels.
// ---------------------------------------------------------------------------
__global__ __launch_bounds__(256, 8) void k_final(const int* __restrict__ wrg,
                                                  const int* __restrict__ epk2,
                                                  const float* __restrict__ qv,
                                                  const float* __restrict__ dinv,
                                                  const float* __restrict__ c0,
                                                  float* __restrict__ out) {
    __shared__ float facc[4][APW];
    int t = threadIdx.x, wv = t >> 6, lane = t & 63;
    int gw = blockIdx.x * 4 + wv;
    if (lane < APW) facc[wv][lane] = 0.0f;
    int beg = wrg[gw * 2], endp = wrg[gw * 2 + 1];
    const int SMASK = (1 << SRC_BITS) - 1;
    for (int j = beg + lane; j < endp; j += 64) {
        int w = epk2[j];
        float val = qv[w & SMASK];
        atomicAdd(&facc[wv][w >> SRC_BITS], val);
    }
    for (int n = lane; n < APW; n += 64) {
        int node = gw * APW + n;
        if (node < N_NODES)
            out[node] = dinv[node] * (qv[node] + facc[wv][n]) + c0[0];
    }
}

// ---------------------------------------------------------------------------
extern "C" void kernel_launch(void* const* d_in, const int* in_sizes, int n_in,
                              void* d_out, int out_size, void* d_ws, size_t ws_size,
                              hipStream_t stream) {
    const float* x  = (const float*)d_in[0];
    const int*   ei = (const int*)d_in[1];
    const int*   src = ei;
    const int*   dst = ei + N_EDGES;
    const float* W1 = (const float*)d_in[2];
    const float* b1 = (const float*)d_in[3];
    const float* W2 = (const float*)d_in[4];
    const float* b2 = (const float*)d_in[5];
    const float* Wc = (const float*)d_in[6];
    const float* bc = (const float*)d_in[7];
    float* out = (float*)d_out;

    char* w = (char*)d_ws;
    int*    bcount  = (int*)w;    w += NBUCK * 4;
    int*    bbase   = (int*)w;    w += (NBUCK + 1) * 4;
    int*    bcur    = (int*)w;    w += NBUCK * 4;
    float*  wc2     = (float*)w;  w += 64 * 4;
    float*  c0      = (float*)w;  w += 4 * 4;
    float*  dinv    = (float*)w;  w += (size_t)N_NODES * 4;
    float*  q       = (float*)w;  w += ((size_t)N_NODES + 4) * 4;   // +1 zero slot
    int*    wrg     = (int*)w;    w += (size_t)NWAVES * 2 * 4;
    int*    epk2    = (int*)w;    w += (size_t)NBUCK * BCAP * 4;    // 16.8 MB
    // packT and bufA liveness is disjoint (packT dead after k_partB) -> alias
    char*   shared_region = w;
    int*    packT   = (int*)shared_region;    // N_EDGES*4 = 12.8 MB
    __half* bufA    = (__half*)shared_region; // (N_NODES+1)*128 B = 12.8 MB
    w += (size_t)N_EDGES * 4 + 256;

    const int NB_BH = (int)(((long long)N_EDGES + BH_C - 1) / BH_C);  // 196
    const int NB_PA = (int)(((long long)N_EDGES + PA_C - 1) / PA_C);  // 782
    const int NB_G  = (N_NODES + NTB) / NTB;                          // 782 (covers zero row)
    const int NB_W  = NWAVES / 4;                                     // 1472

    hipMemsetAsync(bcount, 0, NBUCK * 4, stream);
    k_bhist<<<NB_BH, BH_T, 0, stream>>>(dst, bcount);
    k_bscan<<<1, NBUCK, 0, stream>>>(bcount, bbase, bcur);
    k_wc2  <<<1, 64, 0, stream>>>(W2, Wc, b2, bc, wc2, c0, q);
    k_partA<<<NB_PA, PA_T, 0, stream>>>(src, dst, bcur, packT);
    k_partB<<<NBUCK, PB_T, 0, stream>>>(bbase, packT, dinv, epk2, wrg);

    // layer 1: gemm -> hs fp16 (overwrites packT space); streamed aggregate -> q
    k_gemm1<<<NB_G, GT, 0, stream>>>(x, W1, dinv, bufA);
    k_agg3 <<<NB_W, 256, 0, stream>>>(wrg, epk2, bufA, dinv, b1, wc2, q);

    // collapsed layer 2 + head
    k_final<<<NB_W, 256, 0, stream>>>(wrg, epk2, q, dinv, c0, out);
}